// Round 7
// baseline (554.028 us; speedup 1.0000x reference)
//
#include <hip/hip_runtime.h>
#include <hip/hip_bf16.h>

#define HC 128
#define NHEAD 4
#define NEG 0.2f

typedef unsigned int uint32;

__device__ __forceinline__ float leaky(float v) { return v > 0.f ? v : NEG * v; }
__device__ __forceinline__ int clampi(int v, int lo, int hi) { return v < lo ? lo : (v > hi ? hi : v); }

__device__ __forceinline__ uint32 pack_bf16(float lo, float hi) {
  uint32 a = __float_as_uint(lo);
  uint32 b = __float_as_uint(hi);
  a = (a + 0x7FFFu + ((a >> 16) & 1u)) >> 16;
  b = (b + 0x7FFFu + ((b >> 16) & 1u)) & 0xFFFF0000u;
  return a | b;
}
__device__ __forceinline__ float2 unpack_bf16(uint32 u) {
  return make_float2(__uint_as_float(u << 16), __uint_as_float(u & 0xFFFF0000u));
}

// ---------------- utility ----------------
__global__ __launch_bounds__(256) void zero_kernel(int* __restrict__ p, int n) {
  int i = blockIdx.x * 256 + threadIdx.x;
  int stride = gridDim.x * 256;
  for (; i < n; i += stride) p[i] = 0;
}

// ---------------- CSR build ----------------
__global__ __launch_bounds__(256) void hist_kernel(const int* __restrict__ dst, int* __restrict__ cnt, int E, int n) {
  int e = blockIdx.x * 256 + threadIdx.x;
  if (e < E) {
    int d = clampi(dst[e], 0, n - 1);
    atomicAdd(&cnt[d], 1);
  }
}

__global__ __launch_bounds__(256) void scan_pass1(const int* __restrict__ cnt, int* __restrict__ blocksum, int n) {
  __shared__ int red[256];
  int t = threadIdx.x;
  int i = blockIdx.x * 256 + t;
  red[t] = i < n ? cnt[i] : 0;
  __syncthreads();
  for (int off = 128; off >= 1; off >>= 1) {
    if (t < off) red[t] += red[t + off];
    __syncthreads();
  }
  if (t == 0) blocksum[blockIdx.x] = red[0];
}

__global__ __launch_bounds__(256) void scan_pass2(const int* __restrict__ blocksum, int* __restrict__ blockpre,
                                                  int* __restrict__ row_start, int NB, int n) {
  __shared__ int part[256];
  int t = threadIdx.x;
  int chunk = (NB + 255) >> 8;
  int lo = t * chunk; if (lo > NB) lo = NB;
  int hi = lo + chunk; if (hi > NB) hi = NB;
  int s = 0;
  for (int i = lo; i < hi; ++i) s += blocksum[i];
  part[t] = s;
  __syncthreads();
  for (int off = 1; off < 256; off <<= 1) {
    int v = (t >= off) ? part[t - off] : 0;
    __syncthreads();
    part[t] += v;
    __syncthreads();
  }
  int run = part[t] - s;
  for (int i = lo; i < hi; ++i) {
    blockpre[i] = run;
    run += blocksum[i];
  }
  if (t == 255) row_start[n] = part[255];
}

__global__ __launch_bounds__(256) void scan_pass3(const int* __restrict__ cnt, const int* __restrict__ blockpre,
                                                  int* __restrict__ row_start, int* __restrict__ cursor, int n) {
  __shared__ int part[256];
  int t = threadIdx.x;
  int i = blockIdx.x * 256 + t;
  int c = i < n ? cnt[i] : 0;
  part[t] = c;
  __syncthreads();
  for (int off = 1; off < 256; off <<= 1) {
    int v = (t >= off) ? part[t - off] : 0;
    __syncthreads();
    part[t] += v;
    __syncthreads();
  }
  int excl = part[t] - c;
  if (i < n) {
    int b = blockpre[blockIdx.x] + excl;
    row_start[i] = b;
    cursor[i] = b;
  }
}

// scatter: also record dst node per CSR position (for per-layer edge_exp)
__global__ __launch_bounds__(256) void scatter_kernel(const int* __restrict__ src, const int* __restrict__ dst,
                                                      int* __restrict__ cursor, int* __restrict__ csr,
                                                      int* __restrict__ dpos, int E, int n) {
  int e = blockIdx.x * 256 + threadIdx.x;
  if (e < E) {
    int d = clampi(dst[e], 0, n - 1);
    int s = clampi(src[e], 0, n - 1);
    int p = atomicAdd(&cursor[d], 1);
    if (p >= 0 && p < E) { csr[p] = s; dpos[p] = d; }
  }
}

// ---------------- per-layer, per-CSR-slot attention weight ----------------
// pexp[p][h] = exp(leaky(As[csr[p]][h] + Ad[dpos[p]][h])); E-parallel.
__global__ __launch_bounds__(256) void edge_exp(const int* __restrict__ csr, const int* __restrict__ dpos,
                                                const float* __restrict__ As, const float* __restrict__ Ad,
                                                float4* __restrict__ pexp, int E) {
  int p = blockIdx.x * 256 + threadIdx.x;
  if (p >= E) return;
  int s = csr[p], d = dpos[p];
  float4 a = *(const float4*)&As[(size_t)s * 4];
  float4 b = *(const float4*)&Ad[(size_t)d * 4];
  float4 r;
  r.x = __expf(leaky(a.x + b.x));
  r.y = __expf(leaky(a.y + b.y));
  r.z = __expf(leaky(a.z + b.z));
  r.w = __expf(leaky(a.w + b.w));
  pexp[p] = r;
}

// ---------------- GEMM: H = X @ W, fused attention-coefficient epilogue ----------
template <bool BF16IN>
__global__ __launch_bounds__(256) void gemm_gat(const void* __restrict__ Xv, const float* __restrict__ W,
                                                const float* __restrict__ a_src, const float* __restrict__ a_dst,
                                                uint32* __restrict__ H16, float* __restrict__ As,
                                                float* __restrict__ Ad, int n) {
  constexpr int XS_WORDS = BF16IN ? 64 * 64 : 64 * 128;
  __shared__ uint32 Xs[XS_WORDS];
  int t = threadIdx.x;
  int row0 = blockIdx.x * 64;
  if constexpr (BF16IN) {
    const uint32* X16 = (const uint32*)Xv;
    for (int i = t; i < 1024; i += 256) {
      int r = i >> 4, c4 = i & 15;
      int gr = row0 + r; if (gr >= n) gr = n - 1;
      ((uint4*)Xs)[i] = ((const uint4*)X16)[(size_t)gr * 16 + c4];
    }
  } else {
    const float* X = (const float*)Xv;
    for (int i = t; i < 2048; i += 256) {
      int r = i >> 5, c4 = i & 31;
      int gr = row0 + r; if (gr >= n) gr = n - 1;
      ((uint4*)Xs)[i] = ((const uint4*)X)[(size_t)gr * 32 + c4];
    }
  }
  __syncthreads();
  int wave = t >> 6, lane = t & 63;
  int r0 = wave * 16;
  int c0 = 2 * lane;
  float acc[16][2];
#pragma unroll
  for (int r = 0; r < 16; ++r) { acc[r][0] = 0.f; acc[r][1] = 0.f; }
  for (int k = 0; k < 128; k += 4) {
    float2 wv[4];
#pragma unroll
    for (int kk = 0; kk < 4; ++kk) wv[kk] = *(const float2*)&W[(size_t)(k + kk) * 128 + c0];
#pragma unroll
    for (int r = 0; r < 16; ++r) {
      float x0, x1, x2, x3;
      if constexpr (BF16IN) {
        uint2 xu = *(const uint2*)&Xs[(r0 + r) * 64 + (k >> 1)];
        float2 ab = unpack_bf16(xu.x), cd = unpack_bf16(xu.y);
        x0 = ab.x; x1 = ab.y; x2 = cd.x; x3 = cd.y;
      } else {
        float4 xv = *(const float4*)&((const float*)Xs)[(r0 + r) * 128 + k];
        x0 = xv.x; x1 = xv.y; x2 = xv.z; x3 = xv.w;
      }
      acc[r][0] += x0 * wv[0].x + x1 * wv[1].x + x2 * wv[2].x + x3 * wv[3].x;
      acc[r][1] += x0 * wv[0].y + x1 * wv[1].y + x2 * wv[2].y + x3 * wv[3].y;
    }
  }
  float2 asv = *(const float2*)&a_src[c0];
  float2 adv = *(const float2*)&a_dst[c0];
#pragma unroll
  for (int r = 0; r < 16; ++r) {
    int gr = row0 + r0 + r;
    float ps = acc[r][0] * asv.x + acc[r][1] * asv.y;
    float pd = acc[r][0] * adv.x + acc[r][1] * adv.y;
#pragma unroll
    for (int off = 1; off < 16; off <<= 1) {
      ps += __shfl_xor(ps, off);
      pd += __shfl_xor(pd, off);
    }
    if (gr < n) {
      H16[(size_t)gr * 64 + lane] = pack_bf16(acc[r][0], acc[r][1]);
      if ((lane & 15) == 0) {
        As[gr * 4 + (lane >> 4)] = ps;
        Ad[gr * 4 + (lane >> 4)] = pd;
      }
    }
  }
}

// ---------------- aggregation: 2 nodes per wave, precomputed alpha ----------------
// Per edge: 1 shfl (src id) + 1 sequential 4B alpha load (broadcast within the
// 16-lane head group; denominator accumulates for free) + 1 H16 gather + 2 FMA.
// No per-edge exp, no As gather, no alpha shfl, no final reduce.
template <bool OUTFP32>
__global__ __launch_bounds__(256) void agg_kernel(const uint32* __restrict__ H16, const float* __restrict__ As,
                                                  const float* __restrict__ Ad, const int* __restrict__ row_start,
                                                  const int* __restrict__ csr, const float4* __restrict__ pexp,
                                                  const float* __restrict__ bias, void* __restrict__ outv, int n) {
  int wv = (blockIdx.x * 256 + threadIdx.x) >> 6;
  int lane = threadIdx.x & 63;
  int w0 = wv * 2, w1 = wv * 2 + 1;
  if (w0 >= n) return;
  bool has1 = w1 < n;
  int hsel = lane >> 4;
  int base0 = row_start[w0], deg0 = row_start[w0 + 1] - base0;
  int base1 = 0, deg1 = 0;
  if (has1) { base1 = row_start[w1]; deg1 = row_start[w1 + 1] - base1; }
  if (deg0 < 0) deg0 = 0;
  if (deg1 < 0) deg1 = 0;
  float p0 = __expf(leaky(As[w0 * 4 + hsel] + Ad[w0 * 4 + hsel]));
  float p1 = has1 ? __expf(leaky(As[w1 * 4 + hsel] + Ad[w1 * 4 + hsel])) : 0.f;
  float2 hv0 = unpack_bf16(H16[(size_t)w0 * 64 + lane]);
  float2 hv1 = has1 ? unpack_bf16(H16[(size_t)w1 * 64 + lane]) : make_float2(0.f, 0.f);
  float den0 = p0, den1 = p1;
  float acc00 = p0 * hv0.x, acc01 = p0 * hv0.y;
  float acc10 = p1 * hv1.x, acc11 = p1 * hv1.y;
  int mdeg = deg0 > deg1 ? deg0 : deg1;
  for (int chunk = 0; chunk < mdeg; chunk += 64) {
    int j = chunk + lane;
    int sm0 = (j < deg0) ? csr[base0 + j] : 0;
    int sm1 = (has1 && j < deg1) ? csr[base1 + j] : 0;
    int c0 = deg0 - chunk; if (c0 > 64) c0 = 64; if (c0 < 0) c0 = 0;
    int c1 = deg1 - chunk; if (c1 > 64) c1 = 64; if (c1 < 0) c1 = 0;
    int cm = c0 > c1 ? c0 : c1;
    for (int u = 0; u < cm; ++u) {
      int s0 = __shfl(sm0, u);
      int s1 = __shfl(sm1, u);
      if (u < c0) {
        float aw = ((const float*)&pexp[base0 + chunk + u])[hsel];
        den0 += aw;
        float2 h2 = unpack_bf16(H16[(size_t)s0 * 64 + lane]);
        acc00 += aw * h2.x;
        acc01 += aw * h2.y;
      }
      if (u < c1) {
        float aw = ((const float*)&pexp[base1 + chunk + u])[hsel];
        den1 += aw;
        float2 h2 = unpack_bf16(H16[(size_t)s1 * 64 + lane]);
        acc10 += aw * h2.x;
        acc11 += aw * h2.y;
      }
    }
  }
  float2 bv = *(const float2*)&bias[2 * lane];
  {
    float inv = 1.f / den0;
    float r0 = fmaxf(acc00 * inv + bv.x, 0.f);
    float r1 = fmaxf(acc01 * inv + bv.y, 0.f);
    if constexpr (OUTFP32) ((float2*)outv)[(size_t)w0 * 64 + lane] = make_float2(r0, r1);
    else ((uint32*)outv)[(size_t)w0 * 64 + lane] = pack_bf16(r0, r1);
  }
  if (has1) {
    float inv = 1.f / den1;
    float r0 = fmaxf(acc10 * inv + bv.x, 0.f);
    float r1 = fmaxf(acc11 * inv + bv.y, 0.f);
    if constexpr (OUTFP32) ((float2*)outv)[(size_t)w1 * 64 + lane] = make_float2(r0, r1);
    else ((uint32*)outv)[(size_t)w1 * 64 + lane] = pack_bf16(r0, r1);
  }
}

// ---------------- pooling ----------------
__global__ __launch_bounds__(128) void pool_kernel(const float* __restrict__ X, const int* __restrict__ batch,
                                                   float* __restrict__ pooled, int n, int G) {
  int c = threadIdx.x;
  int n0 = blockIdx.x * 64;
  if (n0 >= n) return;
  int end = n0 + 64 < n ? n0 + 64 : n;
  int curg = clampi(batch[n0], 0, G - 1);
  float acc = 0.f;
  for (int i = n0; i < end; ++i) {
    int g = clampi(batch[i], 0, G - 1);
    if (g != curg) {
      atomicAdd(&pooled[curg * 128 + c], acc);
      acc = 0.f;
      curg = g;
    }
    acc += X[(size_t)i * 128 + c];
  }
  atomicAdd(&pooled[curg * 128 + c], acc);
}

__global__ __launch_bounds__(64) void logits_kernel(const float* __restrict__ pooled, const float* __restrict__ Wh,
                                                    const float* __restrict__ bh, float* __restrict__ out) {
  int g = blockIdx.x, lane = threadIdx.x;
  float p0 = pooled[g * 128 + lane];
  float p1 = pooled[g * 128 + lane + 64];
  for (int o = 0; o < 10; ++o) {
    float v = p0 * Wh[lane * 10 + o] + p1 * Wh[(lane + 64) * 10 + o];
#pragma unroll
    for (int off = 32; off >= 1; off >>= 1) v += __shfl_xor(v, off);
    if (lane == 0) out[g * 10 + o] = v + bh[o];
  }
}

extern "C" void kernel_launch(void* const* d_in, const int* in_sizes, int n_in,
                              void* d_out, int out_size, void* d_ws, size_t ws_size,
                              hipStream_t stream) {
  const float *x, *Wl[3], *asr[3], *adr[3], *bias[3], *Wh, *bh;
  const int *edge_index, *batch;
  long long E_ll;
  if (n_in >= 17) {
    x = (const float*)d_in[0];
    for (int l = 0; l < 3; ++l) {
      Wl[l] = (const float*)d_in[1 + l];
      asr[l] = (const float*)d_in[4 + l];
      adr[l] = (const float*)d_in[7 + l];
      bias[l] = (const float*)d_in[10 + l];
    }
    Wh = (const float*)d_in[13];
    bh = (const float*)d_in[14];
    edge_index = (const int*)d_in[15];
    batch = (const int*)d_in[16];
    E_ll = (long long)in_sizes[15] / 2;
  } else if (n_in >= 9) {
    x = (const float*)d_in[0];
    const float* Wc = (const float*)d_in[1];
    const float* ac = (const float*)d_in[2];
    const float* dc = (const float*)d_in[3];
    const float* bc = (const float*)d_in[4];
    for (int l = 0; l < 3; ++l) {
      Wl[l] = Wc + (size_t)l * HC * HC;
      asr[l] = ac + (size_t)l * HC;
      adr[l] = dc + (size_t)l * HC;
      bias[l] = bc + (size_t)l * HC;
    }
    Wh = (const float*)d_in[5];
    bh = (const float*)d_in[6];
    edge_index = (const int*)d_in[7];
    batch = (const int*)d_in[8];
    E_ll = (long long)in_sizes[7] / 2;
  } else {
    zero_kernel<<<(out_size + 255) / 256, 256, 0, stream>>>((int*)d_out, out_size);
    return;
  }
  int N = in_sizes[0] / HC;
  int G = out_size / 10;
  if (N <= 0 || G <= 0 || E_ll <= 0 || E_ll > (1LL << 30)) {
    zero_kernel<<<(out_size + 255) / 256, 256, 0, stream>>>((int*)d_out, out_size);
    return;
  }
  int E = (int)E_ll;
  int NB = (N + 255) / 256;

  char* w = (char*)d_ws;
  size_t off = 0;
  auto take = [&](size_t bytes) -> char* {
    char* p = w + off;
    off = (off + bytes + 511) & ~(size_t)511;
    return p;
  };
  uint32* H16 = (uint32*)take((size_t)N * 64 * 4);
  uint32* X16 = (uint32*)take((size_t)N * 64 * 4);
  float* bufQ = (float*)take((size_t)N * HC * 4);
  float* As = (float*)take((size_t)N * NHEAD * 4);
  float* Ad = (float*)take((size_t)N * NHEAD * 4);
  int* cnt = (int*)take((size_t)N * 4);
  int* row_start = (int*)take((size_t)(N + 1) * 4);
  int* cursor = (int*)take((size_t)N * 4);
  int* csr = (int*)take((size_t)E * 4);
  int* dpos = (int*)take((size_t)E * 4);
  float4* pexp = (float4*)take((size_t)E * 16);
  int* blocksum = (int*)take((size_t)NB * 4);
  int* blockpre = (int*)take((size_t)NB * 4);
  float* pooled = (float*)take((size_t)G * HC * 4);

  if (off > ws_size) {
    zero_kernel<<<(out_size + 255) / 256, 256, 0, stream>>>((int*)d_out, out_size);
    return;
  }

  const int* esrc = edge_index;
  const int* edst = edge_index + E;

  zero_kernel<<<(N + 255) / 256, 256, 0, stream>>>(cnt, N);
  hist_kernel<<<(E + 255) / 256, 256, 0, stream>>>(edst, cnt, E, N);
  scan_pass1<<<NB, 256, 0, stream>>>(cnt, blocksum, N);
  scan_pass2<<<1, 256, 0, stream>>>(blocksum, blockpre, row_start, NB, N);
  scan_pass3<<<NB, 256, 0, stream>>>(cnt, blockpre, row_start, cursor, N);
  scatter_kernel<<<(E + 255) / 256, 256, 0, stream>>>(esrc, edst, cursor, csr, dpos, E, N);

  int gemm_grid = (N + 63) / 64;
  int agg_grid = (N + 7) / 8;  // 2 nodes per wave, 4 waves per block
  int ee_grid = (E + 255) / 256;

  // layer 0: fp32 x -> H16; agg -> bf16 X16
  gemm_gat<false><<<gemm_grid, 256, 0, stream>>>(x, Wl[0], asr[0], adr[0], H16, As, Ad, N);
  edge_exp<<<ee_grid, 256, 0, stream>>>(csr, dpos, As, Ad, pexp, E);
  agg_kernel<false><<<agg_grid, 256, 0, stream>>>(H16, As, Ad, row_start, csr, pexp, bias[0], X16, N);
  // layer 1
  gemm_gat<true><<<gemm_grid, 256, 0, stream>>>(X16, Wl[1], asr[1], adr[1], H16, As, Ad, N);
  edge_exp<<<ee_grid, 256, 0, stream>>>(csr, dpos, As, Ad, pexp, E);
  agg_kernel<false><<<agg_grid, 256, 0, stream>>>(H16, As, Ad, row_start, csr, pexp, bias[1], X16, N);
  // layer 2: agg -> fp32 bufQ
  gemm_gat<true><<<gemm_grid, 256, 0, stream>>>(X16, Wl[2], asr[2], adr[2], H16, As, Ad, N);
  edge_exp<<<ee_grid, 256, 0, stream>>>(csr, dpos, As, Ad, pexp, E);
  agg_kernel<true><<<agg_grid, 256, 0, stream>>>(H16, As, Ad, row_start, csr, pexp, bias[2], bufQ, N);

  zero_kernel<<<(G * HC + 255) / 256, 256, 0, stream>>>((int*)pooled, G * HC);
  pool_kernel<<<(N + 63) / 64, 128, 0, stream>>>(bufQ, batch, pooled, N, G);
  logits_kernel<<<G, 64, 0, stream>>>(pooled, Wh, bh, (float*)d_out);
}

// Round 8
// 431.025 us; speedup vs baseline: 1.2854x; 1.2854x over previous
//
#include <hip/hip_runtime.h>
#include <hip/hip_bf16.h>

#define HC 128
#define NHEAD 4
#define NEG 0.2f

typedef unsigned int uint32;

__device__ __forceinline__ float leaky(float v) { return v > 0.f ? v : NEG * v; }
__device__ __forceinline__ int clampi(int v, int lo, int hi) { return v < lo ? lo : (v > hi ? hi : v); }

__device__ __forceinline__ uint32 pack_bf16(float lo, float hi) {
  uint32 a = __float_as_uint(lo);
  uint32 b = __float_as_uint(hi);
  a = (a + 0x7FFFu + ((a >> 16) & 1u)) >> 16;
  b = (b + 0x7FFFu + ((b >> 16) & 1u)) & 0xFFFF0000u;
  return a | b;
}
__device__ __forceinline__ float2 unpack_bf16(uint32 u) {
  return make_float2(__uint_as_float(u << 16), __uint_as_float(u & 0xFFFF0000u));
}

// ---------------- utility ----------------
__global__ __launch_bounds__(256) void zero_kernel(int* __restrict__ p, int n) {
  int i = blockIdx.x * 256 + threadIdx.x;
  int stride = gridDim.x * 256;
  for (; i < n; i += stride) p[i] = 0;
}

// ---------------- CSR build ----------------
__global__ __launch_bounds__(256) void hist_kernel(const int* __restrict__ dst, int* __restrict__ cnt, int E, int n) {
  int e = blockIdx.x * 256 + threadIdx.x;
  if (e < E) {
    int d = clampi(dst[e], 0, n - 1);
    atomicAdd(&cnt[d], 1);
  }
}

__global__ __launch_bounds__(256) void scan_pass1(const int* __restrict__ cnt, int* __restrict__ blocksum, int n) {
  __shared__ int red[256];
  int t = threadIdx.x;
  int i = blockIdx.x * 256 + t;
  red[t] = i < n ? cnt[i] : 0;
  __syncthreads();
  for (int off = 128; off >= 1; off >>= 1) {
    if (t < off) red[t] += red[t + off];
    __syncthreads();
  }
  if (t == 0) blocksum[blockIdx.x] = red[0];
}

__global__ __launch_bounds__(256) void scan_pass2(const int* __restrict__ blocksum, int* __restrict__ blockpre,
                                                  int* __restrict__ row_start, int NB, int n) {
  __shared__ int part[256];
  int t = threadIdx.x;
  int chunk = (NB + 255) >> 8;
  int lo = t * chunk; if (lo > NB) lo = NB;
  int hi = lo + chunk; if (hi > NB) hi = NB;
  int s = 0;
  for (int i = lo; i < hi; ++i) s += blocksum[i];
  part[t] = s;
  __syncthreads();
  for (int off = 1; off < 256; off <<= 1) {
    int v = (t >= off) ? part[t - off] : 0;
    __syncthreads();
    part[t] += v;
    __syncthreads();
  }
  int run = part[t] - s;
  for (int i = lo; i < hi; ++i) {
    blockpre[i] = run;
    run += blocksum[i];
  }
  if (t == 255) row_start[n] = part[255];
}

__global__ __launch_bounds__(256) void scan_pass3(const int* __restrict__ cnt, const int* __restrict__ blockpre,
                                                  int* __restrict__ row_start, int* __restrict__ cursor, int n) {
  __shared__ int part[256];
  int t = threadIdx.x;
  int i = blockIdx.x * 256 + t;
  int c = i < n ? cnt[i] : 0;
  part[t] = c;
  __syncthreads();
  for (int off = 1; off < 256; off <<= 1) {
    int v = (t >= off) ? part[t - off] : 0;
    __syncthreads();
    part[t] += v;
    __syncthreads();
  }
  int excl = part[t] - c;
  if (i < n) {
    int b = blockpre[blockIdx.x] + excl;
    row_start[i] = b;
    cursor[i] = b;
  }
}

__global__ __launch_bounds__(256) void scatter_kernel(const int* __restrict__ src, const int* __restrict__ dst,
                                                      int* __restrict__ cursor, int* __restrict__ csr, int E, int n) {
  int e = blockIdx.x * 256 + threadIdx.x;
  if (e < E) {
    int d = clampi(dst[e], 0, n - 1);
    int s = clampi(src[e], 0, n - 1);
    int p = atomicAdd(&cursor[d], 1);
    if (p >= 0 && p < E) csr[p] = s;
  }
}

// ---------------- GEMM: H = X @ W, fused attention-coefficient epilogue ----------
template <bool BF16IN>
__global__ __launch_bounds__(256) void gemm_gat(const void* __restrict__ Xv, const float* __restrict__ W,
                                                const float* __restrict__ a_src, const float* __restrict__ a_dst,
                                                uint32* __restrict__ H16, float* __restrict__ As,
                                                float* __restrict__ Ad, int n) {
  constexpr int XS_WORDS = BF16IN ? 64 * 64 : 64 * 128;
  __shared__ uint32 Xs[XS_WORDS];
  int t = threadIdx.x;
  int row0 = blockIdx.x * 64;
  if constexpr (BF16IN) {
    const uint32* X16 = (const uint32*)Xv;
    for (int i = t; i < 1024; i += 256) {
      int r = i >> 4, c4 = i & 15;
      int gr = row0 + r; if (gr >= n) gr = n - 1;
      ((uint4*)Xs)[i] = ((const uint4*)X16)[(size_t)gr * 16 + c4];
    }
  } else {
    const float* X = (const float*)Xv;
    for (int i = t; i < 2048; i += 256) {
      int r = i >> 5, c4 = i & 31;
      int gr = row0 + r; if (gr >= n) gr = n - 1;
      ((uint4*)Xs)[i] = ((const uint4*)X)[(size_t)gr * 32 + c4];
    }
  }
  __syncthreads();
  int wave = t >> 6, lane = t & 63;
  int r0 = wave * 16;
  int c0 = 2 * lane;
  float acc[16][2];
#pragma unroll
  for (int r = 0; r < 16; ++r) { acc[r][0] = 0.f; acc[r][1] = 0.f; }
  for (int k = 0; k < 128; k += 4) {
    float2 wv[4];
#pragma unroll
    for (int kk = 0; kk < 4; ++kk) wv[kk] = *(const float2*)&W[(size_t)(k + kk) * 128 + c0];
#pragma unroll
    for (int r = 0; r < 16; ++r) {
      float x0, x1, x2, x3;
      if constexpr (BF16IN) {
        uint2 xu = *(const uint2*)&Xs[(r0 + r) * 64 + (k >> 1)];
        float2 ab = unpack_bf16(xu.x), cd = unpack_bf16(xu.y);
        x0 = ab.x; x1 = ab.y; x2 = cd.x; x3 = cd.y;
      } else {
        float4 xv = *(const float4*)&((const float*)Xs)[(r0 + r) * 128 + k];
        x0 = xv.x; x1 = xv.y; x2 = xv.z; x3 = xv.w;
      }
      acc[r][0] += x0 * wv[0].x + x1 * wv[1].x + x2 * wv[2].x + x3 * wv[3].x;
      acc[r][1] += x0 * wv[0].y + x1 * wv[1].y + x2 * wv[2].y + x3 * wv[3].y;
    }
  }
  float2 asv = *(const float2*)&a_src[c0];
  float2 adv = *(const float2*)&a_dst[c0];
#pragma unroll
  for (int r = 0; r < 16; ++r) {
    int gr = row0 + r0 + r;
    float ps = acc[r][0] * asv.x + acc[r][1] * asv.y;
    float pd = acc[r][0] * adv.x + acc[r][1] * adv.y;
#pragma unroll
    for (int off = 1; off < 16; off <<= 1) {
      ps += __shfl_xor(ps, off);
      pd += __shfl_xor(pd, off);
    }
    if (gr < n) {
      H16[(size_t)gr * 64 + lane] = pack_bf16(acc[r][0], acc[r][1]);
      if ((lane & 15) == 0) {
        As[gr * 4 + (lane >> 4)] = ps;
        Ad[gr * 4 + (lane >> 4)] = pd;
      }
    }
  }
}

// ---------------- fused softmax + aggregation (wave per node, 8-deep MLP) --------
// Lane layout: lane = head (lane>>4) x edge-slot (lane&15).
// pm[k] (k=0..3, STATIC indexing) holds exp(leaky(As[src]+Ad[dst])) for edge
// slot (lane&15) of 16-edge group k, head (lane>>4).
// Gather loop: batches of 8 edges -> 8 idx shfls, 8 alpha shfls, 8 independent
// H16 gathers into a register array (forces 8 loads in flight), then 8 FMAs.
// Each lane accumulates the full denominator locally (no final reduce).
template <bool OUTFP32>
__global__ __launch_bounds__(256) void agg_kernel(const uint32* __restrict__ H16, const float* __restrict__ As,
                                                  const float* __restrict__ Ad, const int* __restrict__ row_start,
                                                  const int* __restrict__ csr, const float* __restrict__ bias,
                                                  void* __restrict__ outv, int n) {
  int wid = (blockIdx.x * 256 + threadIdx.x) >> 6;
  int lane = threadIdx.x & 63;
  if (wid >= n) return;
  int base = row_start[wid];
  int deg = row_start[wid + 1] - base;
  if (deg < 0) deg = 0;
  int hsel = lane >> 4;
  float adsel = Ad[wid * 4 + hsel];
  float pself = __expf(leaky(As[wid * 4 + hsel] + adsel));
  float2 hv = unpack_bf16(H16[(size_t)wid * 64 + lane]);
  float den = pself;
  float acc0 = pself * hv.x, acc1 = pself * hv.y;
  for (int chunk = 0; chunk < deg; chunk += 64) {
    int j = chunk + lane;
    int smine = (j < deg) ? clampi(csr[base + j], 0, n - 1) : 0;
    int cnt_ = deg - chunk; if (cnt_ > 64) cnt_ = 64;
    // precompute per-16-edge-group alphas (static register indexing)
    float pm[4];
#pragma unroll
    for (int k = 0; k < 4; ++k) {
      int slot = k * 16 + (lane & 15);
      int sk = __shfl(smine, slot);
      float e = As[sk * 4 + hsel];  // sk=0 when inactive: safe
      pm[k] = (slot < cnt_) ? __expf(leaky(e + adsel)) : 0.f;
    }
#pragma unroll
    for (int k = 0; k < 4; ++k) {
      if (k * 16 >= cnt_) break;  // uniform
#pragma unroll
      for (int b = 0; b < 2; ++b) {
        int u0 = k * 16 + b * 8;
        if (u0 >= cnt_) break;  // uniform
        int ss[8];
        float aw[8];
        float2 h2[8];
#pragma unroll
        for (int i = 0; i < 8; ++i) {
          int u = u0 + i;
          int sv = __shfl(smine, u);
          float av = __shfl(pm[k], (lane & 48) + (u & 15));
          ss[i] = (u < cnt_) ? sv : 0;
          aw[i] = (u < cnt_) ? av : 0.f;
        }
#pragma unroll
        for (int i = 0; i < 8; ++i) h2[i] = unpack_bf16(H16[(size_t)((uint32)ss[i] * 64 + lane)]);
#pragma unroll
        for (int i = 0; i < 8; ++i) {
          den += aw[i];
          acc0 += aw[i] * h2[i].x;
          acc1 += aw[i] * h2[i].y;
        }
      }
    }
  }
  float inv = 1.f / den;
  float2 bv = *(const float2*)&bias[2 * lane];
  float r0v = fmaxf(acc0 * inv + bv.x, 0.f);
  float r1v = fmaxf(acc1 * inv + bv.y, 0.f);
  if constexpr (OUTFP32) {
    ((float2*)outv)[(size_t)wid * 64 + lane] = make_float2(r0v, r1v);
  } else {
    ((uint32*)outv)[(size_t)wid * 64 + lane] = pack_bf16(r0v, r1v);
  }
}

// ---------------- pooling ----------------
__global__ __launch_bounds__(128) void pool_kernel(const float* __restrict__ X, const int* __restrict__ batch,
                                                   float* __restrict__ pooled, int n, int G) {
  int c = threadIdx.x;
  int n0 = blockIdx.x * 64;
  if (n0 >= n) return;
  int end = n0 + 64 < n ? n0 + 64 : n;
  int curg = clampi(batch[n0], 0, G - 1);
  float acc = 0.f;
  for (int i = n0; i < end; ++i) {
    int g = clampi(batch[i], 0, G - 1);
    if (g != curg) {
      atomicAdd(&pooled[curg * 128 + c], acc);
      acc = 0.f;
      curg = g;
    }
    acc += X[(size_t)i * 128 + c];
  }
  atomicAdd(&pooled[curg * 128 + c], acc);
}

__global__ __launch_bounds__(64) void logits_kernel(const float* __restrict__ pooled, const float* __restrict__ Wh,
                                                    const float* __restrict__ bh, float* __restrict__ out) {
  int g = blockIdx.x, lane = threadIdx.x;
  float p0 = pooled[g * 128 + lane];
  float p1 = pooled[g * 128 + lane + 64];
  for (int o = 0; o < 10; ++o) {
    float v = p0 * Wh[lane * 10 + o] + p1 * Wh[(lane + 64) * 10 + o];
#pragma unroll
    for (int off = 32; off >= 1; off >>= 1) v += __shfl_xor(v, off);
    if (lane == 0) out[g * 10 + o] = v + bh[o];
  }
}

extern "C" void kernel_launch(void* const* d_in, const int* in_sizes, int n_in,
                              void* d_out, int out_size, void* d_ws, size_t ws_size,
                              hipStream_t stream) {
  const float *x, *Wl[3], *asr[3], *adr[3], *bias[3], *Wh, *bh;
  const int *edge_index, *batch;
  long long E_ll;
  if (n_in >= 17) {
    x = (const float*)d_in[0];
    for (int l = 0; l < 3; ++l) {
      Wl[l] = (const float*)d_in[1 + l];
      asr[l] = (const float*)d_in[4 + l];
      adr[l] = (const float*)d_in[7 + l];
      bias[l] = (const float*)d_in[10 + l];
    }
    Wh = (const float*)d_in[13];
    bh = (const float*)d_in[14];
    edge_index = (const int*)d_in[15];
    batch = (const int*)d_in[16];
    E_ll = (long long)in_sizes[15] / 2;
  } else if (n_in >= 9) {
    x = (const float*)d_in[0];
    const float* Wc = (const float*)d_in[1];
    const float* ac = (const float*)d_in[2];
    const float* dc = (const float*)d_in[3];
    const float* bc = (const float*)d_in[4];
    for (int l = 0; l < 3; ++l) {
      Wl[l] = Wc + (size_t)l * HC * HC;
      asr[l] = ac + (size_t)l * HC;
      adr[l] = dc + (size_t)l * HC;
      bias[l] = bc + (size_t)l * HC;
    }
    Wh = (const float*)d_in[5];
    bh = (const float*)d_in[6];
    edge_index = (const int*)d_in[7];
    batch = (const int*)d_in[8];
    E_ll = (long long)in_sizes[7] / 2;
  } else {
    zero_kernel<<<(out_size + 255) / 256, 256, 0, stream>>>((int*)d_out, out_size);
    return;
  }
  int N = in_sizes[0] / HC;
  int G = out_size / 10;
  if (N <= 0 || G <= 0 || E_ll <= 0 || E_ll > (1LL << 30)) {
    zero_kernel<<<(out_size + 255) / 256, 256, 0, stream>>>((int*)d_out, out_size);
    return;
  }
  int E = (int)E_ll;
  int NB = (N + 255) / 256;

  char* w = (char*)d_ws;
  size_t off = 0;
  auto take = [&](size_t bytes) -> char* {
    char* p = w + off;
    off = (off + bytes + 511) & ~(size_t)511;
    return p;
  };
  uint32* H16 = (uint32*)take((size_t)N * 64 * 4);
  uint32* X16 = (uint32*)take((size_t)N * 64 * 4);
  float* bufQ = (float*)take((size_t)N * HC * 4);
  float* As = (float*)take((size_t)N * NHEAD * 4);
  float* Ad = (float*)take((size_t)N * NHEAD * 4);
  int* cnt = (int*)take((size_t)N * 4);
  int* row_start = (int*)take((size_t)(N + 1) * 4);
  int* cursor = (int*)take((size_t)N * 4);
  int* csr = (int*)take((size_t)E * 4);
  int* blocksum = (int*)take((size_t)NB * 4);
  int* blockpre = (int*)take((size_t)NB * 4);
  float* pooled = (float*)take((size_t)G * HC * 4);

  if (off > ws_size) {
    zero_kernel<<<(out_size + 255) / 256, 256, 0, stream>>>((int*)d_out, out_size);
    return;
  }

  const int* esrc = edge_index;
  const int* edst = edge_index + E;

  zero_kernel<<<(N + 255) / 256, 256, 0, stream>>>(cnt, N);
  hist_kernel<<<(E + 255) / 256, 256, 0, stream>>>(edst, cnt, E, N);
  scan_pass1<<<NB, 256, 0, stream>>>(cnt, blocksum, N);
  scan_pass2<<<1, 256, 0, stream>>>(blocksum, blockpre, row_start, NB, N);
  scan_pass3<<<NB, 256, 0, stream>>>(cnt, blockpre, row_start, cursor, N);
  scatter_kernel<<<(E + 255) / 256, 256, 0, stream>>>(esrc, edst, cursor, csr, E, N);

  int gemm_grid = (N + 63) / 64;
  int agg_grid = (N + 3) / 4;

  // layer 0: fp32 x -> H16; agg -> bf16 X16
  gemm_gat<false><<<gemm_grid, 256, 0, stream>>>(x, Wl[0], asr[0], adr[0], H16, As, Ad, N);
  agg_kernel<false><<<agg_grid, 256, 0, stream>>>(H16, As, Ad, row_start, csr, bias[0], X16, N);
  // layer 1
  gemm_gat<true><<<gemm_grid, 256, 0, stream>>>(X16, Wl[1], asr[1], adr[1], H16, As, Ad, N);
  agg_kernel<false><<<agg_grid, 256, 0, stream>>>(H16, As, Ad, row_start, csr, bias[1], X16, N);
  // layer 2: agg -> fp32 bufQ
  gemm_gat<true><<<gemm_grid, 256, 0, stream>>>(X16, Wl[2], asr[2], adr[2], H16, As, Ad, N);
  agg_kernel<true><<<agg_grid, 256, 0, stream>>>(H16, As, Ad, row_start, csr, bias[2], bufQ, N);

  zero_kernel<<<(G * HC + 255) / 256, 256, 0, stream>>>((int*)pooled, G * HC);
  pool_kernel<<<(N + 63) / 64, 128, 0, stream>>>(bufQ, batch, pooled, N, G);
  logits_kernel<<<G, 64, 0, stream>>>(pooled, Wh, bh, (float*)d_out);
}

// Round 9
// 378.658 us; speedup vs baseline: 1.4631x; 1.1383x over previous
//
#include <hip/hip_runtime.h>
#include <hip/hip_bf16.h>

#define HC 128
#define NHEAD 4
#define NEG 0.2f

typedef unsigned int uint32;
typedef __attribute__((ext_vector_type(8))) short short8v;   // 8 bf16 = 4 VGPR
typedef __attribute__((ext_vector_type(4))) float f32x4;

__device__ __forceinline__ float leaky(float v) { return v > 0.f ? v : NEG * v; }
__device__ __forceinline__ int clampi(int v, int lo, int hi) { return v < lo ? lo : (v > hi ? hi : v); }

__device__ __forceinline__ uint32 pack_bf16(float lo, float hi) {
  uint32 a = __float_as_uint(lo);
  uint32 b = __float_as_uint(hi);
  a = (a + 0x7FFFu + ((a >> 16) & 1u)) >> 16;
  b = (b + 0x7FFFu + ((b >> 16) & 1u)) & 0xFFFF0000u;
  return a | b;
}
__device__ __forceinline__ unsigned short bf16_1(float v) {
  uint32 a = __float_as_uint(v);
  return (unsigned short)((a + 0x7FFFu + ((a >> 16) & 1u)) >> 16);
}
__device__ __forceinline__ float2 unpack_bf16(uint32 u) {
  return make_float2(__uint_as_float(u << 16), __uint_as_float(u & 0xFFFF0000u));
}
__device__ __forceinline__ short8v as_s8(uint4 u) {
  union { uint4 a; short8v b; } c; c.a = u; return c.b;
}

// ---------------- utility ----------------
__global__ __launch_bounds__(256) void zero_kernel(int* __restrict__ p, int n) {
  int i = blockIdx.x * 256 + threadIdx.x;
  int stride = gridDim.x * 256;
  for (; i < n; i += stride) p[i] = 0;
}

// ---------------- CSR build ----------------
__global__ __launch_bounds__(256) void hist_kernel(const int* __restrict__ dst, int* __restrict__ cnt, int E, int n) {
  int e = blockIdx.x * 256 + threadIdx.x;
  if (e < E) {
    int d = clampi(dst[e], 0, n - 1);
    atomicAdd(&cnt[d], 1);
  }
}

__global__ __launch_bounds__(256) void scan_pass1(const int* __restrict__ cnt, int* __restrict__ blocksum, int n) {
  __shared__ int red[256];
  int t = threadIdx.x;
  int i = blockIdx.x * 256 + t;
  red[t] = i < n ? cnt[i] : 0;
  __syncthreads();
  for (int off = 128; off >= 1; off >>= 1) {
    if (t < off) red[t] += red[t + off];
    __syncthreads();
  }
  if (t == 0) blocksum[blockIdx.x] = red[0];
}

__global__ __launch_bounds__(256) void scan_pass2(const int* __restrict__ blocksum, int* __restrict__ blockpre,
                                                  int* __restrict__ row_start, int NB, int n) {
  __shared__ int part[256];
  int t = threadIdx.x;
  int chunk = (NB + 255) >> 8;
  int lo = t * chunk; if (lo > NB) lo = NB;
  int hi = lo + chunk; if (hi > NB) hi = NB;
  int s = 0;
  for (int i = lo; i < hi; ++i) s += blocksum[i];
  part[t] = s;
  __syncthreads();
  for (int off = 1; off < 256; off <<= 1) {
    int v = (t >= off) ? part[t - off] : 0;
    __syncthreads();
    part[t] += v;
    __syncthreads();
  }
  int run = part[t] - s;
  for (int i = lo; i < hi; ++i) {
    blockpre[i] = run;
    run += blocksum[i];
  }
  if (t == 255) row_start[n] = part[255];
}

__global__ __launch_bounds__(256) void scan_pass3(const int* __restrict__ cnt, const int* __restrict__ blockpre,
                                                  int* __restrict__ row_start, int* __restrict__ cursor, int n) {
  __shared__ int part[256];
  int t = threadIdx.x;
  int i = blockIdx.x * 256 + t;
  int c = i < n ? cnt[i] : 0;
  part[t] = c;
  __syncthreads();
  for (int off = 1; off < 256; off <<= 1) {
    int v = (t >= off) ? part[t - off] : 0;
    __syncthreads();
    part[t] += v;
    __syncthreads();
  }
  int excl = part[t] - c;
  if (i < n) {
    int b = blockpre[blockIdx.x] + excl;
    row_start[i] = b;
    cursor[i] = b;
  }
}

__global__ __launch_bounds__(256) void scatter_kernel(const int* __restrict__ src, const int* __restrict__ dst,
                                                      int* __restrict__ cursor, int* __restrict__ csr, int E, int n) {
  int e = blockIdx.x * 256 + threadIdx.x;
  if (e < E) {
    int d = clampi(dst[e], 0, n - 1);
    int s = clampi(src[e], 0, n - 1);
    int p = atomicAdd(&cursor[d], 1);
    if (p >= 0 && p < E) csr[p] = s;
  }
}

// ---------------- prep: W [128x128 fp32 row-major, 3 layers] -> Wt bf16 [n][k] ----
__global__ __launch_bounds__(256) void wprep(const float* __restrict__ W0, const float* __restrict__ W1,
                                             const float* __restrict__ W2, unsigned short* __restrict__ wt) {
  int g = blockIdx.x * 256 + threadIdx.x;
  if (g >= 3 * 16384) return;
  int l = g >> 14;
  int r = g & 16383;          // r = k*128 + n  (coalesced read)
  int k = r >> 7, nc = r & 127;
  const float* W = l == 0 ? W0 : (l == 1 ? W1 : W2);
  wt[(size_t)l * 16384 + nc * 128 + k] = bf16_1(W[r]);
}

// ---------------- prep: x fp32 [N][128] -> packed bf16 [N][64] ----------------
__global__ __launch_bounds__(256) void xprep(const float* __restrict__ x, uint32* __restrict__ X16, long long n64) {
  long long i = (long long)blockIdx.x * 256 + threadIdx.x;
  if (i >= n64) return;
  float2 v = *(const float2*)&x[i * 2];
  X16[i] = pack_bf16(v.x, v.y);
}

// ---------------- MFMA GEMM: H = X @ W + attention-coefficient epilogue ----------
// bf16 in (packed X16 rows), Wt bf16 [n][k] k-contiguous. Wave owns 16 rows x
// 128 cols = 8 nb-tiles x 4 k-chunks = 32 mfma_f32_16x16x32_bf16.
// A-frag: lane&15 = row, (lane>>4, elem) = k (consistent A/B k-order cancels).
// D layout (verified m89): col = lane&15, row = 4*(lane>>4)+reg.
__global__ __launch_bounds__(256) void gemm_mfma(const uint32* __restrict__ X16, const unsigned short* __restrict__ Wt,
                                                 const float* __restrict__ a_src, const float* __restrict__ a_dst,
                                                 uint32* __restrict__ H16, float* __restrict__ As,
                                                 float* __restrict__ Ad, int n) {
  int t = threadIdx.x;
  int wave = t >> 6, lane = t & 63;
  int l15 = lane & 15, lg = lane >> 4;
  int row0 = blockIdx.x * 64 + wave * 16;
  int arow = row0 + l15;
  if (arow >= n) arow = n - 1;
  const uint4* xr = (const uint4*)(X16 + (size_t)arow * 64);
  uint4 a[4];
#pragma unroll
  for (int kc = 0; kc < 4; ++kc) a[kc] = xr[kc * 4 + lg];
  f32x4 acc[8];
#pragma unroll
  for (int nb = 0; nb < 8; ++nb) acc[nb] = (f32x4){0.f, 0.f, 0.f, 0.f};
#pragma unroll
  for (int kc = 0; kc < 4; ++kc) {
    uint4 b[8];
#pragma unroll
    for (int nb = 0; nb < 8; ++nb) {
      int ncol = nb * 16 + l15;
      b[nb] = *(const uint4*)(Wt + (size_t)ncol * 128 + kc * 32 + lg * 8);
    }
#pragma unroll
    for (int nb = 0; nb < 8; ++nb)
      acc[nb] = __builtin_amdgcn_mfma_f32_16x16x32_bf16(as_s8(a[kc]), as_s8(b[nb]), acc[nb], 0, 0, 0);
  }
  float asv[8], adv[8];
#pragma unroll
  for (int nb = 0; nb < 8; ++nb) {
    asv[nb] = a_src[nb * 16 + l15];
    adv[nb] = a_dst[nb * 16 + l15];
  }
#pragma unroll
  for (int r = 0; r < 4; ++r) {
    int gr = row0 + lg * 4 + r;
    bool ok = gr < n;
    float psh[4], pdh[4];
#pragma unroll
    for (int h = 0; h < 4; ++h) {
      float ps = acc[2 * h][r] * asv[2 * h] + acc[2 * h + 1][r] * asv[2 * h + 1];
      float pd = acc[2 * h][r] * adv[2 * h] + acc[2 * h + 1][r] * adv[2 * h + 1];
#pragma unroll
      for (int off = 1; off < 16; off <<= 1) {
        ps += __shfl_xor(ps, off);
        pd += __shfl_xor(pd, off);
      }
      psh[h] = ps;
      pdh[h] = pd;
    }
    if (ok && l15 == 0) {
#pragma unroll
      for (int h = 0; h < 4; ++h) {
        As[gr * 4 + h] = psh[h];
        Ad[gr * 4 + h] = pdh[h];
      }
    }
#pragma unroll
    for (int nb = 0; nb < 8; ++nb) {
      float mine = acc[nb][r];
      float other = __shfl_xor(mine, 1);
      if (ok && (lane & 1) == 0) H16[(size_t)gr * 64 + nb * 8 + (l15 >> 1)] = pack_bf16(mine, other);
    }
  }
}

// ---------------- fused softmax + aggregation (wave per node, 8-deep MLP) --------
template <bool OUTFP32>
__global__ __launch_bounds__(256) void agg_kernel(const uint32* __restrict__ H16, const float* __restrict__ As,
                                                  const float* __restrict__ Ad, const int* __restrict__ row_start,
                                                  const int* __restrict__ csr, const float* __restrict__ bias,
                                                  void* __restrict__ outv, int n) {
  int wid = (blockIdx.x * 256 + threadIdx.x) >> 6;
  int lane = threadIdx.x & 63;
  if (wid >= n) return;
  int base = row_start[wid];
  int deg = row_start[wid + 1] - base;
  if (deg < 0) deg = 0;
  int hsel = lane >> 4;
  float adsel = Ad[wid * 4 + hsel];
  float pself = __expf(leaky(As[wid * 4 + hsel] + adsel));
  float2 hv = unpack_bf16(H16[(size_t)wid * 64 + lane]);
  float den = pself;
  float acc0 = pself * hv.x, acc1 = pself * hv.y;
  for (int chunk = 0; chunk < deg; chunk += 64) {
    int j = chunk + lane;
    int smine = (j < deg) ? clampi(csr[base + j], 0, n - 1) : 0;
    int cnt_ = deg - chunk; if (cnt_ > 64) cnt_ = 64;
    float pm[4];
#pragma unroll
    for (int k = 0; k < 4; ++k) {
      int slot = k * 16 + (lane & 15);
      int sk = __shfl(smine, slot);
      float e = As[sk * 4 + hsel];
      pm[k] = (slot < cnt_) ? __expf(leaky(e + adsel)) : 0.f;
    }
#pragma unroll
    for (int k = 0; k < 4; ++k) {
      if (k * 16 >= cnt_) break;
#pragma unroll
      for (int b = 0; b < 2; ++b) {
        int u0 = k * 16 + b * 8;
        if (u0 >= cnt_) break;
        int ss[8];
        float aw[8];
        float2 h2[8];
#pragma unroll
        for (int i = 0; i < 8; ++i) {
          int u = u0 + i;
          int sv = __shfl(smine, u);
          float av = __shfl(pm[k], (lane & 48) + (u & 15));
          ss[i] = (u < cnt_) ? sv : 0;
          aw[i] = (u < cnt_) ? av : 0.f;
        }
#pragma unroll
        for (int i = 0; i < 8; ++i) h2[i] = unpack_bf16(H16[(size_t)((uint32)ss[i] * 64 + lane)]);
#pragma unroll
        for (int i = 0; i < 8; ++i) {
          den += aw[i];
          acc0 += aw[i] * h2[i].x;
          acc1 += aw[i] * h2[i].y;
        }
      }
    }
  }
  float inv = 1.f / den;
  float2 bv = *(const float2*)&bias[2 * lane];
  float r0v = fmaxf(acc0 * inv + bv.x, 0.f);
  float r1v = fmaxf(acc1 * inv + bv.y, 0.f);
  if constexpr (OUTFP32) {
    ((float2*)outv)[(size_t)wid * 64 + lane] = make_float2(r0v, r1v);
  } else {
    ((uint32*)outv)[(size_t)wid * 64 + lane] = pack_bf16(r0v, r1v);
  }
}

// ---------------- pooling ----------------
__global__ __launch_bounds__(128) void pool_kernel(const float* __restrict__ X, const int* __restrict__ batch,
                                                   float* __restrict__ pooled, int n, int G) {
  int c = threadIdx.x;
  int n0 = blockIdx.x * 64;
  if (n0 >= n) return;
  int end = n0 + 64 < n ? n0 + 64 : n;
  int curg = clampi(batch[n0], 0, G - 1);
  float acc = 0.f;
  for (int i = n0; i < end; ++i) {
    int g = clampi(batch[i], 0, G - 1);
    if (g != curg) {
      atomicAdd(&pooled[curg * 128 + c], acc);
      acc = 0.f;
      curg = g;
    }
    acc += X[(size_t)i * 128 + c];
  }
  atomicAdd(&pooled[curg * 128 + c], acc);
}

__global__ __launch_bounds__(64) void logits_kernel(const float* __restrict__ pooled, const float* __restrict__ Wh,
                                                    const float* __restrict__ bh, float* __restrict__ out) {
  int g = blockIdx.x, lane = threadIdx.x;
  float p0 = pooled[g * 128 + lane];
  float p1 = pooled[g * 128 + lane + 64];
  for (int o = 0; o < 10; ++o) {
    float v = p0 * Wh[lane * 10 + o] + p1 * Wh[(lane + 64) * 10 + o];
#pragma unroll
    for (int off = 32; off >= 1; off >>= 1) v += __shfl_xor(v, off);
    if (lane == 0) out[g * 10 + o] = v + bh[o];
  }
}

extern "C" void kernel_launch(void* const* d_in, const int* in_sizes, int n_in,
                              void* d_out, int out_size, void* d_ws, size_t ws_size,
                              hipStream_t stream) {
  const float *x, *Wl[3], *asr[3], *adr[3], *bias[3], *Wh, *bh;
  const int *edge_index, *batch;
  long long E_ll;
  if (n_in >= 17) {
    x = (const float*)d_in[0];
    for (int l = 0; l < 3; ++l) {
      Wl[l] = (const float*)d_in[1 + l];
      asr[l] = (const float*)d_in[4 + l];
      adr[l] = (const float*)d_in[7 + l];
      bias[l] = (const float*)d_in[10 + l];
    }
    Wh = (const float*)d_in[13];
    bh = (const float*)d_in[14];
    edge_index = (const int*)d_in[15];
    batch = (const int*)d_in[16];
    E_ll = (long long)in_sizes[15] / 2;
  } else if (n_in >= 9) {
    x = (const float*)d_in[0];
    const float* Wc = (const float*)d_in[1];
    const float* ac = (const float*)d_in[2];
    const float* dc = (const float*)d_in[3];
    const float* bc = (const float*)d_in[4];
    for (int l = 0; l < 3; ++l) {
      Wl[l] = Wc + (size_t)l * HC * HC;
      asr[l] = ac + (size_t)l * HC;
      adr[l] = dc + (size_t)l * HC;
      bias[l] = bc + (size_t)l * HC;
    }
    Wh = (const float*)d_in[5];
    bh = (const float*)d_in[6];
    edge_index = (const int*)d_in[7];
    batch = (const int*)d_in[8];
    E_ll = (long long)in_sizes[7] / 2;
  } else {
    zero_kernel<<<(out_size + 255) / 256, 256, 0, stream>>>((int*)d_out, out_size);
    return;
  }
  int N = in_sizes[0] / HC;
  int G = out_size / 10;
  if (N <= 0 || G <= 0 || E_ll <= 0 || E_ll > (1LL << 30)) {
    zero_kernel<<<(out_size + 255) / 256, 256, 0, stream>>>((int*)d_out, out_size);
    return;
  }
  int E = (int)E_ll;
  int NB = (N + 255) / 256;

  char* w = (char*)d_ws;
  size_t off = 0;
  auto take = [&](size_t bytes) -> char* {
    char* p = w + off;
    off = (off + bytes + 511) & ~(size_t)511;
    return p;
  };
  uint32* H16 = (uint32*)take((size_t)N * 64 * 4);
  uint32* X16 = (uint32*)take((size_t)N * 64 * 4);
  float* bufQ = (float*)take((size_t)N * HC * 4);   // layer-2 fp32 output
  uint32* Xa = (uint32*)bufQ;                        // aliased: bf16 x (used only before bufQ)
  float* As = (float*)take((size_t)N * NHEAD * 4);
  float* Ad = (float*)take((size_t)N * NHEAD * 4);
  int* cnt = (int*)take((size_t)N * 4);
  int* row_start = (int*)take((size_t)(N + 1) * 4);
  int* cursor = (int*)take((size_t)N * 4);
  int* csr = (int*)take((size_t)E * 4);
  int* blocksum = (int*)take((size_t)NB * 4);
  int* blockpre = (int*)take((size_t)NB * 4);
  float* pooled = (float*)take((size_t)G * HC * 4);
  unsigned short* wt16 = (unsigned short*)take((size_t)3 * 16384 * 2);

  if (off > ws_size) {
    zero_kernel<<<(out_size + 255) / 256, 256, 0, stream>>>((int*)d_out, out_size);
    return;
  }

  const int* esrc = edge_index;
  const int* edst = edge_index + E;

  zero_kernel<<<(N + 255) / 256, 256, 0, stream>>>(cnt, N);
  hist_kernel<<<(E + 255) / 256, 256, 0, stream>>>(edst, cnt, E, N);
  scan_pass1<<<NB, 256, 0, stream>>>(cnt, blocksum, N);
  scan_pass2<<<1, 256, 0, stream>>>(blocksum, blockpre, row_start, NB, N);
  scan_pass3<<<NB, 256, 0, stream>>>(cnt, blockpre, row_start, cursor, N);
  scatter_kernel<<<(E + 255) / 256, 256, 0, stream>>>(esrc, edst, cursor, csr, E, N);

  wprep<<<(3 * 16384 + 255) / 256, 256, 0, stream>>>(Wl[0], Wl[1], Wl[2], wt16);
  long long n64 = (long long)N * 64;
  xprep<<<(int)((n64 + 255) / 256), 256, 0, stream>>>(x, Xa, n64);

  int gemm_grid = (N + 63) / 64;
  int agg_grid = (N + 3) / 4;

  // layer 0
  gemm_mfma<<<gemm_grid, 256, 0, stream>>>(Xa, wt16, asr[0], adr[0], H16, As, Ad, N);
  agg_kernel<false><<<agg_grid, 256, 0, stream>>>(H16, As, Ad, row_start, csr, bias[0], X16, N);
  // layer 1
  gemm_mfma<<<gemm_grid, 256, 0, stream>>>(X16, wt16 + 16384, asr[1], adr[1], H16, As, Ad, N);
  agg_kernel<false><<<agg_grid, 256, 0, stream>>>(H16, As, Ad, row_start, csr, bias[1], X16, N);
  // layer 2 (agg -> fp32 bufQ; Xa no longer needed)
  gemm_mfma<<<gemm_grid, 256, 0, stream>>>(X16, wt16 + 2 * 16384, asr[2], adr[2], H16, As, Ad, N);
  agg_kernel<true><<<agg_grid, 256, 0, stream>>>(H16, As, Ad, row_start, csr, bias[2], bufQ, N);

  zero_kernel<<<(G * HC + 255) / 256, 256, 0, stream>>>((int*)pooled, G * HC);
  pool_kernel<<<(N + 63) / 64, 128, 0, stream>>>(bufQ, batch, pooled, N, G);
  logits_kernel<<<G, 64, 0, stream>>>(pooled, Wh, bh, (float*)d_out);
}